// Round 1
// baseline (190.033 us; speedup 1.0000x reference)
//
#include <hip/hip_runtime.h>

// PatchAttacker: B=32 images 512x512x3, N=6 boxes, patch 512x512x3.
// Final pixel = bilinear(patch) of the LAST valid covering patch box, else image.
// Fully parallel: patches sample from `patch` only, so scan order == last-writer-wins.

#define Bn 32
#define Nn 6
#define Hh 512
#define Ww 512
#define Pp 512

__global__ __launch_bounds__(256) void patch_attack_kernel(
    const float* __restrict__ images,  // [B,H,W,3]
    const float* __restrict__ boxes,   // [B,N,4] (ymin,xmin,ymax,xmax)
    const float* __restrict__ patch,   // [P,P,3]
    float* __restrict__ out)           // [B,H,W,3]
{
    // 1024 blocks per image (H*W/256) -> b is wave/block-uniform => s_load for boxes
    const int pix = blockIdx.x * 256 + threadIdx.x;       // global pixel id
    const int b   = blockIdx.x >> 10;                     // 262144 px / 256 = 1024 blocks/img
    const int rem = pix & (Hh * Ww - 1);
    const int y   = rem >> 9;                             // W = 512
    const int x   = rem & (Ww - 1);

    const float* __restrict__ bx = boxes + (size_t)b * Nn * 4;

    float r0, r1, r2;
    bool covered = false;

    // descending n: first valid covering box == last writer in the reference scan
    #pragma unroll
    for (int n = Nn - 1; n >= 0; --n) {
        const float ymin = bx[n * 4 + 0];
        const float xmin = bx[n * 4 + 1];
        const float ymax = bx[n * 4 + 2];
        const float xmax = bx[n * 4 + 3];
        const float h  = ymax - ymin;
        const float w  = xmax - xmin;
        const float pw = h * 0.5f;            // SCALE = 0.5
        const float ph = 1.0f * pw;           // ASPECT = 1.0
        const float oy = ymin + h * 0.5f;
        const float ox = xmin + w * 0.5f;
        float yp = fmaxf(oy - ph * 0.5f, 0.0f);
        float xp = fmaxf(ox - pw * 0.5f, 0.0f);
        yp = (yp + ph > (float)Hh) ? ((float)Hh - ph) : yp;
        xp = (xp + pw > (float)Ww) ? ((float)Ww - pw) : xp;
        const bool valid = ph > 60.0f;        // MIN_PH

        // tf.cast truncation; all quantities >= 0 so C cast matches
        const int y0b = (int)yp;
        const int x0b = (int)xp;
        const int hI  = (int)ph;
        const int wI  = (int)pw;
        const int dy  = y - y0b;
        const int dx  = x - x0b;

        if (valid && dy >= 0 && dy < hI && dx >= 0 && dx < wI) {
            const float hf = (float)(hI > 1 ? hI : 1);
            const float wf = (float)(wI > 1 ? wI : 1);
            float sy = ((float)dy + 0.5f) * ((float)Pp / hf) - 0.5f;
            float sx = ((float)dx + 0.5f) * ((float)Pp / wf) - 0.5f;
            sy = fminf(fmaxf(sy, 0.0f), (float)(Pp - 1));
            sx = fminf(fmaxf(sx, 0.0f), (float)(Pp - 1));
            const int   yl = (int)floorf(sy);
            const int   yh = (yl + 1 < Pp - 1) ? (yl + 1) : (Pp - 1);
            const float wy = sy - (float)yl;
            const int   xl = (int)floorf(sx);
            const int   xh = (xl + 1 < Pp - 1) ? (xl + 1) : (Pp - 1);
            const float wx = sx - (float)xl;

            const float* __restrict__ pll = patch + ((size_t)yl * Pp + xl) * 3;
            const float* __restrict__ plh = patch + ((size_t)yl * Pp + xh) * 3;
            const float* __restrict__ phl = patch + ((size_t)yh * Pp + xl) * 3;
            const float* __restrict__ phh = patch + ((size_t)yh * Pp + xh) * 3;
            const float omwy = 1.0f - wy;
            const float omwx = 1.0f - wx;
            // separable bilinear, same op order as reference (rows over y, then x)
            r0 = (pll[0] * omwy + phl[0] * wy) * omwx + (plh[0] * omwy + phh[0] * wy) * wx;
            r1 = (pll[1] * omwy + phl[1] * wy) * omwx + (plh[1] * omwy + phh[1] * wy) * wx;
            r2 = (pll[2] * omwy + phl[2] * wy) * omwx + (plh[2] * omwy + phh[2] * wy) * wx;
            covered = true;
            break;
        }
    }

    if (!covered) {
        const float* __restrict__ ip = images + (size_t)pix * 3;
        r0 = ip[0];
        r1 = ip[1];
        r2 = ip[2];
    }

    float* __restrict__ op = out + (size_t)pix * 3;
    op[0] = r0;
    op[1] = r1;
    op[2] = r2;
}

extern "C" void kernel_launch(void* const* d_in, const int* in_sizes, int n_in,
                              void* d_out, int out_size, void* d_ws, size_t ws_size,
                              hipStream_t stream) {
    const float* images = (const float*)d_in[0];
    const float* boxes  = (const float*)d_in[1];
    const float* patch  = (const float*)d_in[2];
    float* out = (float*)d_out;

    const int total_pixels = Bn * Hh * Ww;      // 8388608
    const int block = 256;
    const int grid  = total_pixels / block;     // 32768

    patch_attack_kernel<<<grid, block, 0, stream>>>(images, boxes, patch, out);
}